// Round 1
// baseline (399.599 us; speedup 1.0000x reference)
//
#include <hip/hip_runtime.h>

#define N_IMG 64
#define C_CH 256
#define H_IMG 28
#define PADW 30
#define SPIMG 784   // 28*28
#define PADIMG 900  // 30*30
#define SCALE_F 0.02f
#define EPS_F 1e-5f

using short8  = __attribute__((ext_vector_type(8))) short;
using floatx4 = __attribute__((ext_vector_type(4))) float;

__device__ __forceinline__ unsigned short f2bf(float f) {
  unsigned u = __float_as_uint(f);
  return (unsigned short)((u + 0x7fffu + ((u >> 16) & 1u)) >> 16);
}

// ---------------- prep kernels ----------------

// Pack sign(w) as bf16 +-1 into MFMA-A fragment order:
// dst[((off*32 + ci/8)*256 + co)*8 + ci%8], off = kh*3+kw
__global__ void pack_weights(const float* __restrict__ w, unsigned short* __restrict__ ap) {
  int t = blockIdx.x * 256 + threadIdx.x;   // 589824 total
  int j   = t & 7;
  int co  = (t >> 3) & 255;
  int c8  = (t >> 11) & 31;
  int off = t >> 16;          // 0..8
  int ci  = c8 * 8 + j;
  float v = w[(co * 256 + ci) * 9 + off];
  unsigned short b = (v > 0.f) ? 0x3F80u : ((v < 0.f) ? 0xBF80u : 0u);
  ap[t] = b;                  // t == ((off*32+c8)*256+co)*8 + j exactly
}

// bnp: [A1(256) | B1(256) | A2(256) | B2(256)]  y = acc*A + B
__global__ void bn_prep(const float* g1, const float* b1, const float* m1, const float* v1,
                        const float* g2, const float* b2, const float* m2, const float* v2,
                        float* bnp) {
  int c = threadIdx.x;
  float inv1 = g1[c] * rsqrtf(v1[c] + EPS_F);
  bnp[c]       = SCALE_F * inv1;
  bnp[256 + c] = b1[c] - m1[c] * inv1;
  float inv2 = g2[c] * rsqrtf(v2[c] + EPS_F);
  bnp[512 + c] = SCALE_F * inv2;
  bnp[768 + c] = b2[c] - m2[c] * inv2;
}

// x NCHW fp32 -> padded NHWC bf16 (interior only; borders zeroed separately)
__global__ void convert_x(const float* __restrict__ x, unsigned short* __restrict__ xb) {
  __shared__ float tile[28 * 260];   // [w][ci], pitch 260 (1040B, 16B-aligned rows)
  int h = blockIdx.x;                // 0..27
  int n = blockIdx.y;
  int tid = threadIdx.x;
  const float* xs = x + ((size_t)n * C_CH) * SPIMG + h * 28;
  for (int idx = tid; idx < 7168; idx += 256) {      // 256ci * 28w
    int ci = idx / 28;
    int w  = idx - ci * 28;
    tile[w * 260 + ci] = xs[(size_t)ci * SPIMG + w];
  }
  __syncthreads();
  unsigned short* xd = xb + ((size_t)n * PADIMG + (h + 1) * PADW + 1) * C_CH;
  for (int u = tid; u < 1792; u += 256) {            // 28px * 64 chunks(4ci)
    int w  = u >> 6;
    int c4 = u & 63;
    floatx4 f = *(const floatx4*)&tile[w * 260 + c4 * 4];
    ushort4 o;
    o.x = f2bf(f[0]); o.y = f2bf(f[1]); o.z = f2bf(f[2]); o.w = f2bf(f[3]);
    *(ushort4*)(xd + (size_t)w * C_CH + c4 * 4) = o;
  }
}

// zero the 1-px border of a padded NHWC bf16 buffer (116 border px/img * 256 ch)
__global__ void zero_borders(unsigned short* __restrict__ buf) {
  int n = blockIdx.x;
  unsigned short* b = buf + (size_t)n * PADIMG * C_CH;
  for (int u = threadIdx.x; u < 7424; u += 256) {   // 116 px * 64 chunks
    int px = u >> 6, c4 = u & 63;
    int h, w;
    if (px < 30)      { h = 0;       w = px;      }
    else if (px < 60) { h = 29;      w = px - 30; }
    else if (px < 88) { h = px - 59; w = 0;       }
    else              { h = px - 87; w = 29;      }
    ushort4 z = {0, 0, 0, 0};
    *(ushort4*)(b + (size_t)(h * PADW + w) * C_CH + c4 * 4) = z;
  }
}

// ---------------- conv (implicit GEMM) ----------------
// Block: 256 thr = 4 waves. Tile: 128 co x 112 sp of one image.
// Wave w: co [coBlk*128 + w*32, +32), all 112 sp. 14 MFMA(16x16x32 bf16)/K-step.
// K order: ci-block(32) outer, 9 offsets inner (matches Apack chunk = off*32+ci/8).
template<int STAGE>
__global__ __launch_bounds__(256) void bconv(
    const unsigned short* __restrict__ Bin,    // padded NHWC bf16 (xb or abuf)
    const unsigned short* __restrict__ Apack,  // packed +-1 weights
    const float* __restrict__ bnp,
    unsigned short* __restrict__ aout,         // stage1 out (padded NHWC bf16)
    const float* __restrict__ xres,            // stage2 residual (NCHW fp32)
    float* __restrict__ out)                   // stage2 out (NCHW fp32)
{
  __shared__ __align__(16) unsigned short Blds[112 * 40];  // [sp][ci], pitch 40
  __shared__ int pixb[112];

  const int tid  = threadIdx.x;
  const int lane = tid & 63;
  const int wv   = tid >> 6;
  const int quad = lane >> 4;
  const int l16  = lane & 15;
  const int spBlk = blockIdx.x;   // 0..6
  const int coBlk = blockIdx.y;   // 0..1
  const int n     = blockIdx.z;

  if (tid < 112) {
    int m = spBlk * 112 + tid;
    int h = m / 28;
    int w = m - h * 28;
    pixb[tid] = h * PADW + w;     // padded offset of (h+kh, w+kw) = pixb + kh*30 + kw
  }
  __syncthreads();

  const unsigned short* bsrc = Bin + (size_t)n * PADIMG * C_CH;
  const int coW = coBlk * 128 + wv * 32;

  floatx4 acc[2][7];
#pragma unroll
  for (int c = 0; c < 2; ++c)
#pragma unroll
    for (int s = 0; s < 7; ++s)
      acc[c][s] = (floatx4){0.f, 0.f, 0.f, 0.f};

  // staging units: 448 x 16B (112 px * 4 chunks of 8ci); thread does u=tid, tid+256
  const int px0 = tid >> 2, c8_0 = (tid & 3) * 8;
  const int pb0 = pixb[px0];
  const bool has2 = (tid < 192);
  const int px1 = (tid + 256) >> 2;
  const int pb1 = has2 ? pixb[px1] : 0;
  const int c8_1 = c8_0;   // (tid+256)&3 == tid&3
  const int ldsa0 = px0 * 40 + (tid & 3) * 8;
  const int ldsa1 = px1 * 40 + (tid & 3) * 8;

  const int DOFF[9] = {0, 1, 2, 30, 31, 32, 60, 61, 62};

#pragma unroll 1
  for (int cib = 0; cib < 256; cib += 32) {
#pragma unroll
    for (int off = 0; off < 9; ++off) {
      const int doff = DOFF[off];
      __syncthreads();   // previous step's frag reads complete
      {
        const unsigned short* s0 = bsrc + (size_t)(pb0 + doff) * C_CH + cib + c8_0;
        *(short8*)&Blds[ldsa0] = *(const short8*)s0;
        if (has2) {
          const unsigned short* s1 = bsrc + (size_t)(pb1 + doff) * C_CH + cib + c8_1;
          *(short8*)&Blds[ldsa1] = *(const short8*)s1;
        }
      }
      __syncthreads();
      const int chunk = off * 32 + (cib >> 3) + quad;
      short8 a0 = *(const short8*)(Apack + (size_t)(chunk * 256 + coW + l16) * 8);
      short8 a1 = *(const short8*)(Apack + (size_t)(chunk * 256 + coW + 16 + l16) * 8);
#pragma unroll
      for (int s = 0; s < 7; ++s) {
        short8 b = *(const short8*)&Blds[(s * 16 + l16) * 40 + quad * 8];
        acc[0][s] = __builtin_amdgcn_mfma_f32_16x16x32_bf16(a0, b, acc[0][s], 0, 0, 0);
        acc[1][s] = __builtin_amdgcn_mfma_f32_16x16x32_bf16(a1, b, acc[1][s], 0, 0, 0);
      }
    }
  }

  // Epilogue. C/D layout: col(sp)=lane&15, row(co within 16-tile)=quad*4+reg.
  if (STAGE == 1) {
#pragma unroll
    for (int c = 0; c < 2; ++c) {
      int co = coW + c * 16 + quad * 4;
      floatx4 As = *(const floatx4*)(bnp + co);
      floatx4 Bs = *(const floatx4*)(bnp + 256 + co);
#pragma unroll
      for (int s = 0; s < 7; ++s) {
        int pix = pixb[s * 16 + l16] + PADW + 1;   // (h+1,w+1) in padded coords
        unsigned short* dst = aout + ((size_t)n * PADIMG + pix) * C_CH + co;
        ushort4 o;
        o.x = f2bf(fmaxf(acc[c][s][0] * As[0] + Bs[0], 0.f));
        o.y = f2bf(fmaxf(acc[c][s][1] * As[1] + Bs[1], 0.f));
        o.z = f2bf(fmaxf(acc[c][s][2] * As[2] + Bs[2], 0.f));
        o.w = f2bf(fmaxf(acc[c][s][3] * As[3] + Bs[3], 0.f));
        *(ushort4*)dst = o;
      }
    }
  } else {
#pragma unroll
    for (int c = 0; c < 2; ++c) {
      int co = coW + c * 16 + quad * 4;
      floatx4 As = *(const floatx4*)(bnp + 512 + co);
      floatx4 Bs = *(const floatx4*)(bnp + 768 + co);
#pragma unroll
      for (int s = 0; s < 7; ++s) {
        int m = spBlk * 112 + s * 16 + l16;
#pragma unroll
        for (int r = 0; r < 4; ++r) {
          size_t oidx = ((size_t)n * C_CH + co + r) * SPIMG + m;
          float v = acc[c][s][r] * As[r] + Bs[r] + xres[oidx];
          out[oidx] = fmaxf(v, 0.f);
        }
      }
    }
  }
}

// ---------------- launch ----------------

extern "C" void kernel_launch(void* const* d_in, const int* in_sizes, int n_in,
                              void* d_out, int out_size, void* d_ws, size_t ws_size,
                              hipStream_t stream) {
  const float* x  = (const float*)d_in[0];
  const float* w1 = (const float*)d_in[1];
  const float* g1 = (const float*)d_in[2];
  const float* b1 = (const float*)d_in[3];
  const float* m1 = (const float*)d_in[4];
  const float* v1 = (const float*)d_in[5];
  const float* w2 = (const float*)d_in[6];
  const float* g2 = (const float*)d_in[7];
  const float* b2 = (const float*)d_in[8];
  const float* m2 = (const float*)d_in[9];
  const float* v2 = (const float*)d_in[10];
  float* out = (float*)d_out;

  char* ws = (char*)d_ws;
  const size_t PADBUF = (size_t)N_IMG * PADIMG * C_CH * 2;  // 29,491,200 B
  const size_t WPACK  = 589824ull * 2;                       // 1,179,648 B
  unsigned short* xb   = (unsigned short*)ws;
  unsigned short* abuf = (unsigned short*)(ws + PADBUF);
  unsigned short* ap1  = (unsigned short*)(ws + 2 * PADBUF);
  unsigned short* ap2  = (unsigned short*)(ws + 2 * PADBUF + WPACK);
  float* bnp           = (float*)(ws + 2 * PADBUF + 2 * WPACK);

  zero_borders<<<N_IMG, 256, 0, stream>>>(xb);
  zero_borders<<<N_IMG, 256, 0, stream>>>(abuf);
  pack_weights<<<2304, 256, 0, stream>>>(w1, ap1);
  pack_weights<<<2304, 256, 0, stream>>>(w2, ap2);
  bn_prep<<<1, 256, 0, stream>>>(g1, b1, m1, v1, g2, b2, m2, v2, bnp);
  convert_x<<<dim3(28, N_IMG), 256, 0, stream>>>(x, xb);

  dim3 grid(7, 2, N_IMG);   // sp-tile, co-half, image
  bconv<1><<<grid, 256, 0, stream>>>(xb,   ap1, bnp, abuf, nullptr, nullptr);
  bconv<2><<<grid, 256, 0, stream>>>(abuf, ap2, bnp, nullptr, x, out);
}

// Round 2
// 273.758 us; speedup vs baseline: 1.4597x; 1.4597x over previous
//
#include <hip/hip_runtime.h>

#define N_IMG 64
#define C_CH 256
#define PADW 30
#define SPIMG 784   // 28*28
#define PADIMG 900  // 30*30
#define SCALE_F 0.02f
#define EPS_F 1e-5f

using short8  = __attribute__((ext_vector_type(8))) short;
using floatx4 = __attribute__((ext_vector_type(4))) float;

__device__ __forceinline__ unsigned short f2bf(float f) {
  unsigned u = __float_as_uint(f);
  return (unsigned short)((u + 0x7fffu + ((u >> 16) & 1u)) >> 16);
}

// ---------------- prep kernels ----------------

// Coalesced read of w (NCHW-ish [co][ci][3][3]), scattered 2B store into MFMA-A order:
// ap[((off*32 + ci/8)*256 + co)*8 + ci%8], off = kh*3+kw
__global__ void pack_weights(const float* __restrict__ w1, const float* __restrict__ w2,
                             unsigned short* __restrict__ ap1, unsigned short* __restrict__ ap2) {
  int t = blockIdx.x * 256 + threadIdx.x;   // 589824 total
  const float* __restrict__ w = blockIdx.y ? w2 : w1;
  unsigned short* __restrict__ ap = blockIdx.y ? ap2 : ap1;
  float v = w[t];
  int off = t % 9;
  int ct  = t / 9;            // co*256 + ci
  int ci  = ct & 255;
  int co  = ct >> 8;
  unsigned short b = (v > 0.f) ? 0x3F80u : ((v < 0.f) ? 0xBF80u : 0u);
  ap[((off * 32 + (ci >> 3)) * 256 + co) * 8 + (ci & 7)] = b;
}

// bnp: [A1(256) | B1(256) | A2(256) | B2(256)]  y = acc*A + B
__global__ void bn_prep(const float* g1, const float* b1, const float* m1, const float* v1,
                        const float* g2, const float* b2, const float* m2, const float* v2,
                        float* bnp) {
  int c = threadIdx.x;
  float inv1 = g1[c] * rsqrtf(v1[c] + EPS_F);
  bnp[c]       = SCALE_F * inv1;
  bnp[256 + c] = b1[c] - m1[c] * inv1;
  float inv2 = g2[c] * rsqrtf(v2[c] + EPS_F);
  bnp[512 + c] = SCALE_F * inv2;
  bnp[768 + c] = b2[c] - m2[c] * inv2;
}

// x NCHW fp32 -> padded NHWC bf16 (interior only; borders zeroed separately)
__global__ void convert_x(const float* __restrict__ x, unsigned short* __restrict__ xb) {
  __shared__ float tile[28 * 260];   // [w][ci], pitch 260
  int h = blockIdx.x;                // 0..27
  int n = blockIdx.y;
  int tid = threadIdx.x;
  const float* xs = x + ((size_t)n * C_CH) * SPIMG + h * 28;
  for (int u = tid; u < 1792; u += 256) {      // 256ci * 7 float4 along w
    int ci = u / 7;
    int w4 = u - ci * 7;
    floatx4 f = *(const floatx4*)&xs[(size_t)ci * SPIMG + w4 * 4];
    tile[(w4 * 4 + 0) * 260 + ci] = f[0];
    tile[(w4 * 4 + 1) * 260 + ci] = f[1];
    tile[(w4 * 4 + 2) * 260 + ci] = f[2];
    tile[(w4 * 4 + 3) * 260 + ci] = f[3];
  }
  __syncthreads();
  unsigned short* xd = xb + ((size_t)n * PADIMG + (h + 1) * PADW + 1) * C_CH;
  for (int u = tid; u < 1792; u += 256) {      // 28px * 64 chunks(4ci)
    int w  = u >> 6;
    int c4 = u & 63;
    floatx4 f = *(const floatx4*)&tile[w * 260 + c4 * 4];
    ushort4 o;
    o.x = f2bf(f[0]); o.y = f2bf(f[1]); o.z = f2bf(f[2]); o.w = f2bf(f[3]);
    *(ushort4*)(xd + (size_t)w * C_CH + c4 * 4) = o;
  }
}

// zero the 1-px border of both padded NHWC bf16 buffers
__global__ void zero_borders(unsigned short* __restrict__ xb, unsigned short* __restrict__ abuf) {
  int n = blockIdx.x;
  unsigned short* b = (blockIdx.y ? abuf : xb) + (size_t)n * PADIMG * C_CH;
  for (int u = threadIdx.x; u < 7424; u += 256) {   // 116 px * 64 chunks
    int px = u >> 6, c4 = u & 63;
    int h, w;
    if (px < 30)      { h = 0;       w = px;      }
    else if (px < 60) { h = 29;      w = px - 30; }
    else if (px < 88) { h = px - 59; w = 0;       }
    else              { h = px - 87; w = 29;      }
    ushort4 z = {0, 0, 0, 0};
    *(ushort4*)(b + (size_t)(h * PADW + w) * C_CH + c4 * 4) = z;
  }
}

// ---------------- conv (implicit GEMM, halo-tiled) ----------------
// Block: 256 thr = 4 waves. Macro-tile: 256 co x 112 sp of one image.
// Wave wv: co [wv*64, +64), all 112 sp -> acc 4x7 floatx4 = 112 VGPR.
// K-loop: ci-block(64) outer (LDS halo tile 6 rows x 30 px x 64 ci, pitch 72),
// then 9 offsets x 2 ci-halves from LDS. 2 barriers per ci-block (8 total).
template<int STAGE>
__global__ __launch_bounds__(256, 2) void bconv(
    const unsigned short* __restrict__ Bin,    // padded NHWC bf16 (xb or abuf)
    const unsigned short* __restrict__ Apack,  // packed +-1 weights
    const float* __restrict__ bnp,
    unsigned short* __restrict__ aout,         // stage1 out (padded NHWC bf16)
    const float* __restrict__ xres,            // stage2 residual (NCHW fp32)
    float* __restrict__ out)                   // stage2 out (NCHW fp32)
{
  __shared__ __align__(16) unsigned short Blds[180 * 72];  // [tile-px][ci], pitch 72

  const int tid  = threadIdx.x;
  const int lane = tid & 63;
  const int wv   = tid >> 6;
  const int quad = lane >> 4;
  const int l16  = lane & 15;
  const int spBlk = blockIdx.x;   // 0..6 (rows 4*spBlk .. 4*spBlk+3)
  const int n     = blockIdx.y;

  const int prow0 = 4 * spBlk;              // first padded row of halo tile
  const unsigned short* bsrc = Bin + (size_t)n * PADIMG * C_CH + (size_t)(prow0 * PADW) * C_CH;
  const int coW = wv * 64;

  // per-thread LDS fragment bases (shorts): tile-px (h_loc*30 + w) for each sp-tile s
  int bOff[7];
#pragma unroll
  for (int s = 0; s < 7; ++s) {
    int lm = s * 16 + l16;
    int hl = lm / 28;
    int w  = lm - hl * 28;
    bOff[s] = (hl * 30 + w) * 72 + quad * 8;
  }

  floatx4 acc[4][7];
#pragma unroll
  for (int c = 0; c < 4; ++c)
#pragma unroll
    for (int s = 0; s < 7; ++s)
      acc[c][s] = (floatx4){0.f, 0.f, 0.f, 0.f};

#pragma unroll 1
  for (int cib = 0; cib < 256; cib += 64) {
    __syncthreads();   // previous ci-block's frag reads complete
    // stage 180 px x 64 ci (1440 x 16B units)
    for (int u = tid; u < 1440; u += 256) {
      int px = u >> 3, c8 = (u & 7) * 8;
      const unsigned short* src = bsrc + (size_t)px * C_CH + cib + c8;
      *(short8*)&Blds[px * 72 + c8] = *(const short8*)src;
    }
    __syncthreads();

    const int cbase = (cib >> 3) + quad;
#pragma unroll 1
    for (int kh = 0; kh < 3; ++kh) {
#pragma unroll 1
      for (int kw = 0; kw < 3; ++kw) {
        const int doff72 = (kh * 30 + kw) * 72;
        const int chunkB = (kh * 3 + kw) * 32 + cbase;
#pragma unroll
        for (int half = 0; half < 2; ++half) {
          const int chunk = chunkB + half * 4;
          const unsigned short* apb = Apack + ((size_t)chunk * 256 + coW + l16) * 8;
          short8 a0 = *(const short8*)(apb);
          short8 a1 = *(const short8*)(apb + 16 * 8);
          short8 a2 = *(const short8*)(apb + 32 * 8);
          short8 a3 = *(const short8*)(apb + 48 * 8);
          const int bo = doff72 + half * 32;
#pragma unroll
          for (int s = 0; s < 7; ++s) {
            short8 b = *(const short8*)&Blds[bOff[s] + bo];
            acc[0][s] = __builtin_amdgcn_mfma_f32_16x16x32_bf16(a0, b, acc[0][s], 0, 0, 0);
            acc[1][s] = __builtin_amdgcn_mfma_f32_16x16x32_bf16(a1, b, acc[1][s], 0, 0, 0);
            acc[2][s] = __builtin_amdgcn_mfma_f32_16x16x32_bf16(a2, b, acc[2][s], 0, 0, 0);
            acc[3][s] = __builtin_amdgcn_mfma_f32_16x16x32_bf16(a3, b, acc[3][s], 0, 0, 0);
          }
        }
      }
    }
  }

  // Epilogue. C/D layout: col(sp)=l16, row(co within 16-tile)=quad*4+reg.
  if (STAGE == 1) {
#pragma unroll
    for (int c = 0; c < 4; ++c) {
      int co = coW + c * 16 + quad * 4;
      floatx4 As = *(const floatx4*)(bnp + co);
      floatx4 Bs = *(const floatx4*)(bnp + 256 + co);
#pragma unroll
      for (int s = 0; s < 7; ++s) {
        int lm = s * 16 + l16;
        int hl = lm / 28;
        int w  = lm - hl * 28;
        int pix = (prow0 + hl + 1) * PADW + w + 1;
        unsigned short* dst = aout + ((size_t)n * PADIMG + pix) * C_CH + co;
        ushort4 o;
        o.x = f2bf(fmaxf(acc[c][s][0] * As[0] + Bs[0], 0.f));
        o.y = f2bf(fmaxf(acc[c][s][1] * As[1] + Bs[1], 0.f));
        o.z = f2bf(fmaxf(acc[c][s][2] * As[2] + Bs[2], 0.f));
        o.w = f2bf(fmaxf(acc[c][s][3] * As[3] + Bs[3], 0.f));
        *(ushort4*)dst = o;
      }
    }
  } else {
#pragma unroll
    for (int c = 0; c < 4; ++c) {
      int co = coW + c * 16 + quad * 4;
      floatx4 As = *(const floatx4*)(bnp + 512 + co);
      floatx4 Bs = *(const floatx4*)(bnp + 768 + co);
#pragma unroll
      for (int s = 0; s < 7; ++s) {
        int m = spBlk * 112 + s * 16 + l16;
#pragma unroll
        for (int r = 0; r < 4; ++r) {
          size_t oidx = ((size_t)n * C_CH + co + r) * SPIMG + m;
          float v = acc[c][s][r] * As[r] + Bs[r] + xres[oidx];
          out[oidx] = fmaxf(v, 0.f);
        }
      }
    }
  }
}

// ---------------- launch ----------------

extern "C" void kernel_launch(void* const* d_in, const int* in_sizes, int n_in,
                              void* d_out, int out_size, void* d_ws, size_t ws_size,
                              hipStream_t stream) {
  const float* x  = (const float*)d_in[0];
  const float* w1 = (const float*)d_in[1];
  const float* g1 = (const float*)d_in[2];
  const float* b1 = (const float*)d_in[3];
  const float* m1 = (const float*)d_in[4];
  const float* v1 = (const float*)d_in[5];
  const float* w2 = (const float*)d_in[6];
  const float* g2 = (const float*)d_in[7];
  const float* b2 = (const float*)d_in[8];
  const float* m2 = (const float*)d_in[9];
  const float* v2 = (const float*)d_in[10];
  float* out = (float*)d_out;

  char* ws = (char*)d_ws;
  const size_t PADBUF = (size_t)N_IMG * PADIMG * C_CH * 2;  // 29,491,200 B
  const size_t WPACK  = 589824ull * 2;                       // 1,179,648 B
  unsigned short* xb   = (unsigned short*)ws;
  unsigned short* abuf = (unsigned short*)(ws + PADBUF);
  unsigned short* ap1  = (unsigned short*)(ws + 2 * PADBUF);
  unsigned short* ap2  = (unsigned short*)(ws + 2 * PADBUF + WPACK);
  float* bnp           = (float*)(ws + 2 * PADBUF + 2 * WPACK);

  zero_borders<<<dim3(N_IMG, 2), 256, 0, stream>>>(xb, abuf);
  pack_weights<<<dim3(2304, 2), 256, 0, stream>>>(w1, w2, ap1, ap2);
  bn_prep<<<1, 256, 0, stream>>>(g1, b1, m1, v1, g2, b2, m2, v2, bnp);
  convert_x<<<dim3(28, N_IMG), 256, 0, stream>>>(x, xb);

  dim3 grid(7, N_IMG);   // sp-tile, image
  bconv<1><<<grid, 256, 0, stream>>>(xb,   ap1, bnp, abuf, nullptr, nullptr);
  bconv<2><<<grid, 256, 0, stream>>>(abuf, ap2, bnp, nullptr, x, out);
}